// Round 10
// baseline (399.313 us; speedup 1.0000x reference)
//
#include <hip/hip_runtime.h>

typedef unsigned int uu32;

#define NN 14      // nodes
#define FD 24      // SEQ / feature dim
#define HD 64      // GAT hidden
#define NE 70      // 56 edges + 14 self loops
#define BB 32768   // batch
#define SPW 4      // samples per wave
#define WPB 4      // waves per block
#define K1_BLOCKS (BB / (WPB * SPW))   // 2048
#define K2_BLOCKS (NN * (BB / 256))    // 1792
#define HAP 68     // padded row stride for H1/A1 (16B-aligned rows)
#define H2P 24     // row stride for H2
#define PSZ 224    // dense P rows: 14*16

// Wave-local LDS sync (each wave owns a private slice inside the loop).
#define WSYNC() asm volatile("s_waitcnt lgkmcnt(0)" ::: "memory")

// readlane: pure-VALU wave broadcast, literal lane only (round-4 lesson).
__device__ __forceinline__ float rdl(float v, int l) {
    union { float f; int i; } u;
    u.f = v;
    u.i = __builtin_amdgcn_readlane(u.i, l);
    return u.f;
}

// DPP add-reduce step: x += dpp_shifted(x). Pure VALU, SIMD-local.
// CTRL must be an immediate -> template parameter (r9 compile fix).
template <int CTRL>
__device__ __forceinline__ float dppadd(float x) {
    union { float f; int i; } u, r;
    u.f = x;
    r.i = __builtin_amdgcn_update_dpp(0, u.i, CTRL, 0xf, 0xf, true);
    return x + r.f;
}
// Canonical 64-lane sum: after row_shr 1/2/4/8 + row_bcast:15/31 the FULL
// wave sum sits in lane 63 (other lanes hold partials — only lane 63 used).
__device__ __forceinline__ float dppsum(float x) {
    x = dppadd<0x111>(x);   // row_shr:1
    x = dppadd<0x112>(x);   // row_shr:2
    x = dppadd<0x114>(x);   // row_shr:4
    x = dppadd<0x118>(x);   // row_shr:8
    x = dppadd<0x142>(x);   // row_bcast:15
    x = dppadd<0x143>(x);   // row_bcast:31
    return x;
}

// GAT stage — round-3 structure with ONE change: the S2/S3 H1 LDS
// round-trip (14 ds_write + 32 broadcast ds_read_b128 + a1S staging +
// one WSYNC, ~17% of the wave's shared-LDS-pipe cycles) is replaced by
// DPP cross-lane reduction over the register-resident acc[] (lane = k):
// sd[n] = wave_sum(acc[n] * a1[lane]). Results written from lane 63 as
// packed float4. launch_bounds(256,4) pins VGPR <= 128 (occupancy cliff).
__global__ __launch_bounds__(256, 4) void gat_k(
    const float* __restrict__ x, const int* __restrict__ ei,
    const float* __restrict__ W1, const float* __restrict__ as1,
    const float* __restrict__ ad1, const float* __restrict__ b1,
    const float* __restrict__ W2, const float* __restrict__ as2,
    const float* __restrict__ ad2, const float* __restrict__ b2,
    float* __restrict__ Gout) {
    __shared__ __align__(16) float HA[WPB][NN * HAP];   // A1 (S5->S6)
    __shared__ __align__(16) float H2S[WPB][NN * H2P];
    __shared__ __align__(16) float PS[WPB][PSZ];        // unnormalized exp rows
    __shared__ __align__(16) float sdS[WPB][2 * NN + 4]; // src/dst dots (f4-padded)
    __shared__ float smS[WPB][NN];                      // per-dst exp sums
    __shared__ __align__(16) float a2S[2 * FD];
    __shared__ int esS[NE], edS[NE];

    const int tid = threadIdx.x;
    const int wv = tid >> 6;
    const int lane = tid & 63;
    float* HAw = HA[wv];
    float* H2w = H2S[wv];
    float* Pw = PS[wv];
    float* sdw = sdS[wv];
    float* smw = smS[wv];

    if (tid < 2 * FD) a2S[tid] = (tid < FD) ? as2[tid] : ad2[tid - FD];
    // edge staging: robust to int64 (lo/hi dword pairs) or int32 delivery
    if (tid < 56) {
        int e64 = 1;
        for (int i = 0; i < 8; i++)
            if (ei[2 * i + 1] != 0 || (uu32)ei[2 * i] >= (uu32)NN) e64 = 0;
        esS[tid] = e64 ? ei[2 * tid] : ei[tid];
        edS[tid] = e64 ? ei[112 + 2 * tid] : ei[56 + tid];
    } else if (tid < NE) {
        esS[tid] = tid - 56;   // self loops
        edS[tid] = tid - 56;
    }

    // per-lane resident weights
    float w1r[FD];
#pragma unroll
    for (int f = 0; f < FD; f++) w1r[f] = W1[f * HD + lane];
    const float b1r = b1[lane];
    const float asr = as1[lane];   // conv1 attention vecs, lane = hidden k
    const float adr = ad1[lane];
    const int f2 = lane % FD;
    const int g2 = lane / FD;      // 0,1 active for 24-wide stages
    float w2r[HD];
#pragma unroll
    for (int k = 0; k < HD; k++) w2r[k] = W2[k * FD + f2];
    const float b2r = b2[f2];
    __syncthreads();   // the ONE block barrier: cross-wave staged a2S/es/ed
    // edge ownership: edge0 = lane (0..63); lanes 0..5 also own 64..69
    const bool ex = (lane < NE - 64);
    const int s0 = esS[lane], d0 = edS[lane];
    const int s1 = esS[ex ? 64 + lane : 0], d1 = edS[ex ? 64 + lane : 0];

    const int gw = blockIdx.x * WPB + wv;
#pragma unroll 1
    for (int t = 0; t < SPW; t++) {
        const size_t b = (size_t)gw * SPW + t;
        // ---- 1. X[b] per-lane into regs (coalesced); no LDS staging ----
        const float* __restrict__ xb = x + b * (NN * FD);
        float xr[6];
        xr[0] = xb[lane];
        xr[1] = xb[64 + lane];
        xr[2] = xb[128 + lane];
        xr[3] = xb[192 + lane];
        xr[4] = xb[256 + lane];
        xr[5] = (lane < NN * FD - 320) ? xb[320 + lane] : 0.0f;
        // ---- 2. H1 = X @ W1 (lane owns hidden col); X via readlane ----
        float acc[NN];
#pragma unroll
        for (int n = 0; n < NN; n++) acc[n] = 0.0f;
#pragma unroll
        for (int f = 0; f < FD; f++) {
#pragma unroll
            for (int n = 0; n < NN; n++) {
                const int i = f * NN + n;          // compile-time
                acc[n] = fmaf(rdl(xr[i >> 6], i & 63), w1r[f], acc[n]);
            }
        }
        // (H1 never touches LDS)
        // ---- 3. src/dst dots via DPP reduce over lanes (= hidden k) ----
        {
            float rs[NN];
#pragma unroll
            for (int n = 0; n < NN; n++) rs[n] = dppsum(acc[n] * asr);
            if (lane == 63) {
                *(float4*)&sdw[0] = make_float4(rs[0], rs[1], rs[2], rs[3]);
                *(float4*)&sdw[4] = make_float4(rs[4], rs[5], rs[6], rs[7]);
                *(float4*)&sdw[8] = make_float4(rs[8], rs[9], rs[10], rs[11]);
            }
            float rd[NN];
#pragma unroll
            for (int n = 0; n < NN; n++) rd[n] = dppsum(acc[n] * adr);
            if (lane == 63) {
                *(float4*)&sdw[12] = make_float4(rs[12], rs[13], rd[0], rd[1]);
                *(float4*)&sdw[16] = make_float4(rd[2], rd[3], rd[4], rd[5]);
                *(float4*)&sdw[20] = make_float4(rd[6], rd[7], rd[8], rd[9]);
                *(float4*)&sdw[24] = make_float4(rd[10], rd[11], rd[12], rd[13]);
            }
        }
        if (lane < PSZ / 4)
            *(float4*)&Pw[lane * 4] = make_float4(0.f, 0.f, 0.f, 0.f);
        if (lane < NN) smw[lane] = 0.0f;
        WSYNC();
        // ---- 4. softmax1 (shift-invariant, no max pass: |alpha| << 88) ----
        {
            float a = sdw[s0] + sdw[NN + d0];
            a = a > 0.0f ? a : 0.2f * a;               // leaky_relu(0.2)
            float e0 = __expf(a);
            atomicAdd(&smw[d0], e0);
            atomicAdd(&Pw[d0 * 16 + s0], e0);          // unnormalized
            if (ex) {
                a = sdw[s1] + sdw[NN + d1];
                a = a > 0.0f ? a : 0.2f * a;
                float e1 = __expf(a);
                atomicAdd(&smw[d1], e1);
                atomicAdd(&Pw[d1 * 16 + s1], e1);
            }
        }
        WSYNC();
        // ---- 5. A1 = ELU(P @ H1 / sum + b1); P via rdl gather ----
        const float pr0 = Pw[lane];
        const float pr1 = Pw[64 + lane];
        const float pr2 = Pw[128 + lane];
        const float pr3 = (lane < PSZ - 192) ? Pw[192 + lane] : 0.0f;
        const float smr = (lane < NN) ? smw[lane] : 1.0f;
        float acc2[NN];
#pragma unroll
        for (int n = 0; n < NN; n++) {
            float a = 0.0f;
#pragma unroll
            for (int k = 0; k < NN; k++) {
                const int i = n * 16 + k;          // compile-time
                const float pv = (i < 64) ? rdl(pr0, i) :
                                 (i < 128) ? rdl(pr1, i - 64) :
                                 (i < 192) ? rdl(pr2, i - 128) :
                                             rdl(pr3, i - 192);
                a = fmaf(pv, acc[k], a);
            }
            a = __fdividef(a, rdl(smr, n)) + b1r;
            acc2[n] = a > 0.0f ? a : (__expf(a) - 1.0f);   // ELU
        }
#pragma unroll
        for (int n = 0; n < NN; n++) HAw[n * HAP + lane] = acc2[n];
        WSYNC();
        // ---- 6. H2 = A1 @ W2 : lane (g2,f2) covers 7 nodes ----
        if (g2 < 2) {
#pragma unroll
            for (int i = 0; i < 7; i++) {
                const int n = g2 + 2 * i;
                float a = 0.0f;
#pragma unroll
                for (int k4 = 0; k4 < 16; k4++) {
                    float4 v4 = *(const float4*)&HAw[n * HAP + 4 * k4];
                    a = fmaf(v4.x, w2r[4 * k4 + 0], a);
                    a = fmaf(v4.y, w2r[4 * k4 + 1], a);
                    a = fmaf(v4.z, w2r[4 * k4 + 2], a);
                    a = fmaf(v4.w, w2r[4 * k4 + 3], a);
                }
                H2w[n * H2P + f2] = a;
            }
        }
        WSYNC();
        // ---- 7. conv2 dots (28 lanes) + zero P/sums ----
        if (lane < 2 * NN) {
            const int v = (lane >= NN) ? 1 : 0;
            const int n2 = lane - v * NN;
            float s = 0.0f;
#pragma unroll
            for (int q = 0; q < 6; q++) {
                float4 h4 = *(const float4*)&H2w[n2 * H2P + 4 * q];
                float4 a4 = *(const float4*)&a2S[v * FD + 4 * q];
                s = fmaf(h4.x, a4.x, s); s = fmaf(h4.y, a4.y, s);
                s = fmaf(h4.z, a4.z, s); s = fmaf(h4.w, a4.w, s);
            }
            sdw[v * NN + n2] = s;
        }
        if (lane < PSZ / 4)
            *(float4*)&Pw[lane * 4] = make_float4(0.f, 0.f, 0.f, 0.f);
        if (lane < NN) smw[lane] = 0.0f;
        WSYNC();
        // ---- 8. softmax2 ----
        {
            float a = sdw[s0] + sdw[NN + d0];
            a = a > 0.0f ? a : 0.2f * a;
            float e0 = __expf(a);
            atomicAdd(&smw[d0], e0);
            atomicAdd(&Pw[d0 * 16 + s0], e0);
            if (ex) {
                a = sdw[s1] + sdw[NN + d1];
                a = a > 0.0f ? a : 0.2f * a;
                float e1 = __expf(a);
                atomicAdd(&smw[d1], e1);
                atomicAdd(&Pw[d1 * 16 + s1], e1);
            }
        }
        WSYNC();
        // ---- 9. G = P2 @ H2 / sum + b2 -> d_out [14][B][24] ----
        if (g2 < 2) {
            float h2c[NN];
#pragma unroll
            for (int k = 0; k < NN; k++) h2c[k] = H2w[k * H2P + f2];
#pragma unroll
            for (int i = 0; i < 7; i++) {
                const int n = g2 + 2 * i;
                float a = 0.0f;
#pragma unroll
                for (int k4 = 0; k4 < 3; k4++) {
                    float4 p4 = *(const float4*)&Pw[n * 16 + 4 * k4];
                    a = fmaf(p4.x, h2c[4 * k4 + 0], a);
                    a = fmaf(p4.y, h2c[4 * k4 + 1], a);
                    a = fmaf(p4.z, h2c[4 * k4 + 2], a);
                    a = fmaf(p4.w, h2c[4 * k4 + 3], a);
                }
                float4 p4 = *(const float4*)&Pw[n * 16 + 12];
                a = fmaf(p4.x, h2c[12], a);
                a = fmaf(p4.y, h2c[13], a);
                Gout[((size_t)n * BB + b) * FD + f2] =
                    __fdividef(a, smw[n]) + b2r;
            }
        }
        WSYNC();   // protect reused LDS before next sample (wave-local)
    }
}

// MLP stage, in place on d_out — EXACT round-0 baseline (best measured:
// 133-134 us, reproduced). Every deviation tried (2-row, scalar path,
// readlane streams, permlane split-reads, unroll-2 + hoist) measured
// 137-172 us — this shape is the empirical local optimum. DO NOT perturb.
__global__ __launch_bounds__(256) void mlp_k(
    const float* __restrict__ fc1w, const float* __restrict__ fc1b,
    const float* __restrict__ fc2w, const float* __restrict__ fc2b,
    float* gio) {
    __shared__ __align__(16) float W1L[FD * HD];
    __shared__ __align__(16) float W2L[HD * FD];
    __shared__ float B1L[HD];
    __shared__ float B2L[FD];

    const int t = threadIdx.x;
    const int n = blockIdx.x >> 7;             // 128 blocks per node
    const int b0 = (blockIdx.x & 127) * 256;

    const float4* w1p = (const float4*)(fc1w + (size_t)n * (FD * HD));
    const float4* w2p = (const float4*)(fc2w + (size_t)n * (HD * FD));
    for (int i = t; i < 384; i += 256) {
        *(float4*)&W1L[4 * i] = w1p[i];
        *(float4*)&W2L[4 * i] = w2p[i];
    }
    if (t < HD) B1L[t] = fc1b[n * HD + t];
    if (t < FD) B2L[t] = fc2b[n * FD + t];
    __syncthreads();

    const size_t base = ((size_t)n * BB + b0 + t) * FD;
    float g[FD], o[FD];
#pragma unroll
    for (int q = 0; q < 6; q++)
        *(float4*)&g[4 * q] = *(const float4*)&gio[base + 4 * q];
#pragma unroll
    for (int f = 0; f < FD; f++) o[f] = B2L[f];

#pragma unroll
    for (int j4 = 0; j4 < 16; j4++) {
        float h0 = B1L[4 * j4 + 0], h1 = B1L[4 * j4 + 1];
        float h2 = B1L[4 * j4 + 2], h3 = B1L[4 * j4 + 3];
#pragma unroll
        for (int f = 0; f < FD; f++) {
            float4 w4 = *(const float4*)&W1L[f * HD + 4 * j4];   // broadcast
            h0 = fmaf(g[f], w4.x, h0);
            h1 = fmaf(g[f], w4.y, h1);
            h2 = fmaf(g[f], w4.z, h2);
            h3 = fmaf(g[f], w4.w, h3);
        }
        h0 = fmaxf(h0, 0.f); h1 = fmaxf(h1, 0.f);
        h2 = fmaxf(h2, 0.f); h3 = fmaxf(h3, 0.f);
        float hv[4] = {h0, h1, h2, h3};
#pragma unroll
        for (int u2 = 0; u2 < 4; u2++) {
            const int j = 4 * j4 + u2;
#pragma unroll
            for (int f4 = 0; f4 < 6; f4++) {
                float4 w4 = *(const float4*)&W2L[j * FD + 4 * f4];   // broadcast
                o[4 * f4 + 0] = fmaf(hv[u2], w4.x, o[4 * f4 + 0]);
                o[4 * f4 + 1] = fmaf(hv[u2], w4.y, o[4 * f4 + 1]);
                o[4 * f4 + 2] = fmaf(hv[u2], w4.z, o[4 * f4 + 2]);
                o[4 * f4 + 3] = fmaf(hv[u2], w4.w, o[4 * f4 + 3]);
            }
        }
    }
#pragma unroll
    for (int q = 0; q < 6; q++)
        *(float4*)&gio[base + 4 * q] = *(const float4*)&o[4 * q];
}

extern "C" void kernel_launch(void* const* d_in, const int* in_sizes, int n_in,
                              void* d_out, int out_size, void* d_ws, size_t ws_size,
                              hipStream_t stream) {
    (void)in_sizes; (void)n_in; (void)out_size; (void)d_ws; (void)ws_size;
    const float* x    = (const float*)d_in[0];
    const int*   ei   = (const int*)d_in[1];
    const float* W1   = (const float*)d_in[2];
    const float* as1  = (const float*)d_in[3];
    const float* ad1  = (const float*)d_in[4];
    const float* b1   = (const float*)d_in[5];
    const float* W2   = (const float*)d_in[6];
    const float* as2  = (const float*)d_in[7];
    const float* ad2  = (const float*)d_in[8];
    const float* b2   = (const float*)d_in[9];
    const float* fc1w = (const float*)d_in[10];
    const float* fc1b = (const float*)d_in[11];
    const float* fc2w = (const float*)d_in[12];
    const float* fc2b = (const float*)d_in[13];
    float* gio = (float*)d_out;   // G staged in d_out, MLP rewrites in place

    gat_k<<<dim3(K1_BLOCKS), dim3(256), 0, stream>>>(
        x, ei, W1, as1, ad1, b1, W2, as2, ad2, b2, gio);
    mlp_k<<<dim3(K2_BLOCKS), dim3(256), 0, stream>>>(
        fc1w, fc1b, fc2w, fc2b, gio);
}

// Round 11
// 322.648 us; speedup vs baseline: 1.2376x; 1.2376x over previous
//
#include <hip/hip_runtime.h>

typedef unsigned int uu32;

#define NN 14      // nodes
#define FD 24      // SEQ / feature dim
#define HD 64      // GAT hidden
#define NE 70      // 56 edges + 14 self loops
#define BB 32768   // batch
#define SPW 4      // samples per wave
#define WPB 4      // waves per block
#define K1_BLOCKS (BB / (WPB * SPW))   // 2048
#define K2_BLOCKS (NN * (BB / 256))    // 1792
#define HAP 68     // padded row stride for H1/A1 (16B-aligned rows)
#define H2P 24     // row stride for H2
#define PSZ 224    // dense P rows: 14*16

// Wave-local LDS sync (each wave owns a private slice inside the loop).
#define WSYNC() asm volatile("s_waitcnt lgkmcnt(0)" ::: "memory")

// readlane: pure-VALU wave broadcast, literal lane only (round-4 lesson).
__device__ __forceinline__ float rdl(float v, int l) {
    union { float f; int i; } u;
    u.f = v;
    u.i = __builtin_amdgcn_readlane(u.i, l);
    return u.f;
}

// DPP add-reduce step: x += dpp_shifted(x). Pure VALU, SIMD-local.
// CTRL must be an immediate -> template parameter.
template <int CTRL>
__device__ __forceinline__ float dppadd(float x) {
    union { float f; int i; } u, r;
    u.f = x;
    r.i = __builtin_amdgcn_update_dpp(0, u.i, CTRL, 0xf, 0xf, true);
    return x + r.f;
}
// Canonical 64-lane sum: after row_shr 1/2/4/8 + row_bcast:15/31 the FULL
// wave sum sits in lane 63 (other lanes hold partials — only lane 63 used).
__device__ __forceinline__ float dppsum(float x) {
    x = dppadd<0x111>(x);   // row_shr:1
    x = dppadd<0x112>(x);   // row_shr:2
    x = dppadd<0x114>(x);   // row_shr:4
    x = dppadd<0x118>(x);   // row_shr:8
    x = dppadd<0x142>(x);   // row_bcast:15
    x = dppadd<0x143>(x);   // row_bcast:31
    return x;
}

// GAT stage — round-3 structure + DPP attention dots (S2/S3's H1 LDS
// round-trip replaced by wave-reduction over register-resident acc[]).
// ROUND-10 LESSON: __launch_bounds__(256,4) made the compiler allocate 64
// VGPRs and spill w1r/w2r to scratch (FETCH 21.7GB -> 516GB, +60us). Plain
// __launch_bounds__(256) (round-3's bound, 100 VGPR, zero spill) restored.
__global__ __launch_bounds__(256) void gat_k(
    const float* __restrict__ x, const int* __restrict__ ei,
    const float* __restrict__ W1, const float* __restrict__ as1,
    const float* __restrict__ ad1, const float* __restrict__ b1,
    const float* __restrict__ W2, const float* __restrict__ as2,
    const float* __restrict__ ad2, const float* __restrict__ b2,
    float* __restrict__ Gout) {
    __shared__ __align__(16) float HA[WPB][NN * HAP];   // A1 (S5->S6)
    __shared__ __align__(16) float H2S[WPB][NN * H2P];
    __shared__ __align__(16) float PS[WPB][PSZ];        // unnormalized exp rows
    __shared__ __align__(16) float sdS[WPB][2 * NN + 4]; // src/dst dots (f4-padded)
    __shared__ float smS[WPB][NN];                      // per-dst exp sums
    __shared__ __align__(16) float a2S[2 * FD];
    __shared__ int esS[NE], edS[NE];

    const int tid = threadIdx.x;
    const int wv = tid >> 6;
    const int lane = tid & 63;
    float* HAw = HA[wv];
    float* H2w = H2S[wv];
    float* Pw = PS[wv];
    float* sdw = sdS[wv];
    float* smw = smS[wv];

    if (tid < 2 * FD) a2S[tid] = (tid < FD) ? as2[tid] : ad2[tid - FD];
    // edge staging: robust to int64 (lo/hi dword pairs) or int32 delivery
    if (tid < 56) {
        int e64 = 1;
        for (int i = 0; i < 8; i++)
            if (ei[2 * i + 1] != 0 || (uu32)ei[2 * i] >= (uu32)NN) e64 = 0;
        esS[tid] = e64 ? ei[2 * tid] : ei[tid];
        edS[tid] = e64 ? ei[112 + 2 * tid] : ei[56 + tid];
    } else if (tid < NE) {
        esS[tid] = tid - 56;   // self loops
        edS[tid] = tid - 56;
    }

    // per-lane resident weights
    float w1r[FD];
#pragma unroll
    for (int f = 0; f < FD; f++) w1r[f] = W1[f * HD + lane];
    const float b1r = b1[lane];
    const float asr = as1[lane];   // conv1 attention vecs, lane = hidden k
    const float adr = ad1[lane];
    const int f2 = lane % FD;
    const int g2 = lane / FD;      // 0,1 active for 24-wide stages
    float w2r[HD];
#pragma unroll
    for (int k = 0; k < HD; k++) w2r[k] = W2[k * FD + f2];
    const float b2r = b2[f2];
    __syncthreads();   // the ONE block barrier: cross-wave staged a2S/es/ed
    // edge ownership: edge0 = lane (0..63); lanes 0..5 also own 64..69
    const bool ex = (lane < NE - 64);
    const int s0 = esS[lane], d0 = edS[lane];
    const int s1 = esS[ex ? 64 + lane : 0], d1 = edS[ex ? 64 + lane : 0];

    const int gw = blockIdx.x * WPB + wv;
#pragma unroll 1
    for (int t = 0; t < SPW; t++) {
        const size_t b = (size_t)gw * SPW + t;
        // ---- 1. X[b] per-lane into regs (coalesced); no LDS staging ----
        const float* __restrict__ xb = x + b * (NN * FD);
        float xr[6];
        xr[0] = xb[lane];
        xr[1] = xb[64 + lane];
        xr[2] = xb[128 + lane];
        xr[3] = xb[192 + lane];
        xr[4] = xb[256 + lane];
        xr[5] = (lane < NN * FD - 320) ? xb[320 + lane] : 0.0f;
        // ---- 2. H1 = X @ W1 (lane owns hidden col); X via readlane ----
        float acc[NN];
#pragma unroll
        for (int n = 0; n < NN; n++) acc[n] = 0.0f;
#pragma unroll
        for (int f = 0; f < FD; f++) {
#pragma unroll
            for (int n = 0; n < NN; n++) {
                const int i = f * NN + n;          // compile-time
                acc[n] = fmaf(rdl(xr[i >> 6], i & 63), w1r[f], acc[n]);
            }
        }
        // (H1 never touches LDS)
        // ---- 3. src/dst dots via DPP reduce over lanes (= hidden k) ----
        {
            float rs[NN];
#pragma unroll
            for (int n = 0; n < NN; n++) rs[n] = dppsum(acc[n] * asr);
            if (lane == 63) {
                *(float4*)&sdw[0] = make_float4(rs[0], rs[1], rs[2], rs[3]);
                *(float4*)&sdw[4] = make_float4(rs[4], rs[5], rs[6], rs[7]);
                *(float4*)&sdw[8] = make_float4(rs[8], rs[9], rs[10], rs[11]);
            }
            float rd[NN];
#pragma unroll
            for (int n = 0; n < NN; n++) rd[n] = dppsum(acc[n] * adr);
            if (lane == 63) {
                *(float4*)&sdw[12] = make_float4(rs[12], rs[13], rd[0], rd[1]);
                *(float4*)&sdw[16] = make_float4(rd[2], rd[3], rd[4], rd[5]);
                *(float4*)&sdw[20] = make_float4(rd[6], rd[7], rd[8], rd[9]);
                *(float4*)&sdw[24] = make_float4(rd[10], rd[11], rd[12], rd[13]);
            }
        }
        if (lane < PSZ / 4)
            *(float4*)&Pw[lane * 4] = make_float4(0.f, 0.f, 0.f, 0.f);
        if (lane < NN) smw[lane] = 0.0f;
        WSYNC();
        // ---- 4. softmax1 (shift-invariant, no max pass: |alpha| << 88) ----
        {
            float a = sdw[s0] + sdw[NN + d0];
            a = a > 0.0f ? a : 0.2f * a;               // leaky_relu(0.2)
            float e0 = __expf(a);
            atomicAdd(&smw[d0], e0);
            atomicAdd(&Pw[d0 * 16 + s0], e0);          // unnormalized
            if (ex) {
                a = sdw[s1] + sdw[NN + d1];
                a = a > 0.0f ? a : 0.2f * a;
                float e1 = __expf(a);
                atomicAdd(&smw[d1], e1);
                atomicAdd(&Pw[d1 * 16 + s1], e1);
            }
        }
        WSYNC();
        // ---- 5. A1 = ELU(P @ H1 / sum + b1); P via rdl gather ----
        const float pr0 = Pw[lane];
        const float pr1 = Pw[64 + lane];
        const float pr2 = Pw[128 + lane];
        const float pr3 = (lane < PSZ - 192) ? Pw[192 + lane] : 0.0f;
        const float smr = (lane < NN) ? smw[lane] : 1.0f;
        float acc2[NN];
#pragma unroll
        for (int n = 0; n < NN; n++) {
            float a = 0.0f;
#pragma unroll
            for (int k = 0; k < NN; k++) {
                const int i = n * 16 + k;          // compile-time
                const float pv = (i < 64) ? rdl(pr0, i) :
                                 (i < 128) ? rdl(pr1, i - 64) :
                                 (i < 192) ? rdl(pr2, i - 128) :
                                             rdl(pr3, i - 192);
                a = fmaf(pv, acc[k], a);
            }
            a = __fdividef(a, rdl(smr, n)) + b1r;
            acc2[n] = a > 0.0f ? a : (__expf(a) - 1.0f);   // ELU
        }
#pragma unroll
        for (int n = 0; n < NN; n++) HAw[n * HAP + lane] = acc2[n];
        WSYNC();
        // ---- 6. H2 = A1 @ W2 : lane (g2,f2) covers 7 nodes ----
        if (g2 < 2) {
#pragma unroll
            for (int i = 0; i < 7; i++) {
                const int n = g2 + 2 * i;
                float a = 0.0f;
#pragma unroll
                for (int k4 = 0; k4 < 16; k4++) {
                    float4 v4 = *(const float4*)&HAw[n * HAP + 4 * k4];
                    a = fmaf(v4.x, w2r[4 * k4 + 0], a);
                    a = fmaf(v4.y, w2r[4 * k4 + 1], a);
                    a = fmaf(v4.z, w2r[4 * k4 + 2], a);
                    a = fmaf(v4.w, w2r[4 * k4 + 3], a);
                }
                H2w[n * H2P + f2] = a;
            }
        }
        WSYNC();
        // ---- 7. conv2 dots (28 lanes) + zero P/sums ----
        if (lane < 2 * NN) {
            const int v = (lane >= NN) ? 1 : 0;
            const int n2 = lane - v * NN;
            float s = 0.0f;
#pragma unroll
            for (int q = 0; q < 6; q++) {
                float4 h4 = *(const float4*)&H2w[n2 * H2P + 4 * q];
                float4 a4 = *(const float4*)&a2S[v * FD + 4 * q];
                s = fmaf(h4.x, a4.x, s); s = fmaf(h4.y, a4.y, s);
                s = fmaf(h4.z, a4.z, s); s = fmaf(h4.w, a4.w, s);
            }
            sdw[v * NN + n2] = s;
        }
        if (lane < PSZ / 4)
            *(float4*)&Pw[lane * 4] = make_float4(0.f, 0.f, 0.f, 0.f);
        if (lane < NN) smw[lane] = 0.0f;
        WSYNC();
        // ---- 8. softmax2 ----
        {
            float a = sdw[s0] + sdw[NN + d0];
            a = a > 0.0f ? a : 0.2f * a;
            float e0 = __expf(a);
            atomicAdd(&smw[d0], e0);
            atomicAdd(&Pw[d0 * 16 + s0], e0);
            if (ex) {
                a = sdw[s1] + sdw[NN + d1];
                a = a > 0.0f ? a : 0.2f * a;
                float e1 = __expf(a);
                atomicAdd(&smw[d1], e1);
                atomicAdd(&Pw[d1 * 16 + s1], e1);
            }
        }
        WSYNC();
        // ---- 9. G = P2 @ H2 / sum + b2 -> d_out [14][B][24] ----
        if (g2 < 2) {
            float h2c[NN];
#pragma unroll
            for (int k = 0; k < NN; k++) h2c[k] = H2w[k * H2P + f2];
#pragma unroll
            for (int i = 0; i < 7; i++) {
                const int n = g2 + 2 * i;
                float a = 0.0f;
#pragma unroll
                for (int k4 = 0; k4 < 3; k4++) {
                    float4 p4 = *(const float4*)&Pw[n * 16 + 4 * k4];
                    a = fmaf(p4.x, h2c[4 * k4 + 0], a);
                    a = fmaf(p4.y, h2c[4 * k4 + 1], a);
                    a = fmaf(p4.z, h2c[4 * k4 + 2], a);
                    a = fmaf(p4.w, h2c[4 * k4 + 3], a);
                }
                float4 p4 = *(const float4*)&Pw[n * 16 + 12];
                a = fmaf(p4.x, h2c[12], a);
                a = fmaf(p4.y, h2c[13], a);
                Gout[((size_t)n * BB + b) * FD + f2] =
                    __fdividef(a, smw[n]) + b2r;
            }
        }
        WSYNC();   // protect reused LDS before next sample (wave-local)
    }
}

// MLP stage, in place on d_out — EXACT round-0 baseline (best measured:
// 133-134 us, reproduced). Every deviation tried (2-row, scalar path,
// readlane streams, permlane split-reads, unroll-2 + hoist) measured
// 137-172 us — this shape is the empirical local optimum. DO NOT perturb.
__global__ __launch_bounds__(256) void mlp_k(
    const float* __restrict__ fc1w, const float* __restrict__ fc1b,
    const float* __restrict__ fc2w, const float* __restrict__ fc2b,
    float* gio) {
    __shared__ __align__(16) float W1L[FD * HD];
    __shared__ __align__(16) float W2L[HD * FD];
    __shared__ float B1L[HD];
    __shared__ float B2L[FD];

    const int t = threadIdx.x;
    const int n = blockIdx.x >> 7;             // 128 blocks per node
    const int b0 = (blockIdx.x & 127) * 256;

    const float4* w1p = (const float4*)(fc1w + (size_t)n * (FD * HD));
    const float4* w2p = (const float4*)(fc2w + (size_t)n * (HD * FD));
    for (int i = t; i < 384; i += 256) {
        *(float4*)&W1L[4 * i] = w1p[i];
        *(float4*)&W2L[4 * i] = w2p[i];
    }
    if (t < HD) B1L[t] = fc1b[n * HD + t];
    if (t < FD) B2L[t] = fc2b[n * FD + t];
    __syncthreads();

    const size_t base = ((size_t)n * BB + b0 + t) * FD;
    float g[FD], o[FD];
#pragma unroll
    for (int q = 0; q < 6; q++)
        *(float4*)&g[4 * q] = *(const float4*)&gio[base + 4 * q];
#pragma unroll
    for (int f = 0; f < FD; f++) o[f] = B2L[f];

#pragma unroll
    for (int j4 = 0; j4 < 16; j4++) {
        float h0 = B1L[4 * j4 + 0], h1 = B1L[4 * j4 + 1];
        float h2 = B1L[4 * j4 + 2], h3 = B1L[4 * j4 + 3];
#pragma unroll
        for (int f = 0; f < FD; f++) {
            float4 w4 = *(const float4*)&W1L[f * HD + 4 * j4];   // broadcast
            h0 = fmaf(g[f], w4.x, h0);
            h1 = fmaf(g[f], w4.y, h1);
            h2 = fmaf(g[f], w4.z, h2);
            h3 = fmaf(g[f], w4.w, h3);
        }
        h0 = fmaxf(h0, 0.f); h1 = fmaxf(h1, 0.f);
        h2 = fmaxf(h2, 0.f); h3 = fmaxf(h3, 0.f);
        float hv[4] = {h0, h1, h2, h3};
#pragma unroll
        for (int u2 = 0; u2 < 4; u2++) {
            const int j = 4 * j4 + u2;
#pragma unroll
            for (int f4 = 0; f4 < 6; f4++) {
                float4 w4 = *(const float4*)&W2L[j * FD + 4 * f4];   // broadcast
                o[4 * f4 + 0] = fmaf(hv[u2], w4.x, o[4 * f4 + 0]);
                o[4 * f4 + 1] = fmaf(hv[u2], w4.y, o[4 * f4 + 1]);
                o[4 * f4 + 2] = fmaf(hv[u2], w4.z, o[4 * f4 + 2]);
                o[4 * f4 + 3] = fmaf(hv[u2], w4.w, o[4 * f4 + 3]);
            }
        }
    }
#pragma unroll
    for (int q = 0; q < 6; q++)
        *(float4*)&gio[base + 4 * q] = *(const float4*)&o[4 * q];
}

extern "C" void kernel_launch(void* const* d_in, const int* in_sizes, int n_in,
                              void* d_out, int out_size, void* d_ws, size_t ws_size,
                              hipStream_t stream) {
    (void)in_sizes; (void)n_in; (void)out_size; (void)d_ws; (void)ws_size;
    const float* x    = (const float*)d_in[0];
    const int*   ei   = (const int*)d_in[1];
    const float* W1   = (const float*)d_in[2];
    const float* as1  = (const float*)d_in[3];
    const float* ad1  = (const float*)d_in[4];
    const float* b1   = (const float*)d_in[5];
    const float* W2   = (const float*)d_in[6];
    const float* as2  = (const float*)d_in[7];
    const float* ad2  = (const float*)d_in[8];
    const float* b2   = (const float*)d_in[9];
    const float* fc1w = (const float*)d_in[10];
    const float* fc1b = (const float*)d_in[11];
    const float* fc2w = (const float*)d_in[12];
    const float* fc2b = (const float*)d_in[13];
    float* gio = (float*)d_out;   // G staged in d_out, MLP rewrites in place

    gat_k<<<dim3(K1_BLOCKS), dim3(256), 0, stream>>>(
        x, ei, W1, as1, ad1, b1, W2, as2, ad2, b2, gio);
    mlp_k<<<dim3(K2_BLOCKS), dim3(256), 0, stream>>>(
        fc1w, fc1b, fc2w, fc2b, gio);
}

// Round 12
// 307.933 us; speedup vs baseline: 1.2968x; 1.0478x over previous
//
#include <hip/hip_runtime.h>

typedef unsigned int uu32;

#define NN 14      // nodes
#define FD 24      // SEQ / feature dim
#define HD 64      // GAT hidden
#define NE 70      // 56 edges + 14 self loops
#define BB 32768   // batch
#define SPW 4      // samples per wave
#define WPB 4      // waves per block
#define K1_BLOCKS (BB / (WPB * SPW))   // 2048
#define K2_BLOCKS (NN * (BB / 256))    // 1792
#define HAP 68     // padded row stride for H1/A1 (16B-aligned rows)
#define H2P 24     // row stride for H2
#define PSZ 224    // dense P rows: 14*16

// Wave-local LDS sync (each wave owns a private slice inside the loop).
#define WSYNC() asm volatile("s_waitcnt lgkmcnt(0)" ::: "memory")

// readlane: pure-VALU wave broadcast, literal lane only (round-4 lesson).
__device__ __forceinline__ float rdl(float v, int l) {
    union { float f; int i; } u;
    u.f = v;
    u.i = __builtin_amdgcn_readlane(u.i, l);
    return u.f;
}

// DPP add-reduce step: x += dpp_shifted(x). Pure VALU, SIMD-local.
// CTRL must be an immediate -> template parameter.
template <int CTRL>
__device__ __forceinline__ float dppadd(float x) {
    union { float f; int i; } u, r;
    u.f = x;
    r.i = __builtin_amdgcn_update_dpp(0, u.i, CTRL, 0xf, 0xf, true);
    return x + r.f;
}
// Canonical 64-lane sum: after row_shr 1/2/4/8 + row_bcast:15/31 the FULL
// wave sum sits in lane 63 (other lanes hold partials — only lane 63 used).
__device__ __forceinline__ float dppsum(float x) {
    x = dppadd<0x111>(x);   // row_shr:1
    x = dppadd<0x112>(x);   // row_shr:2
    x = dppadd<0x114>(x);   // row_shr:4
    x = dppadd<0x118>(x);   // row_shr:8
    x = dppadd<0x142>(x);   // row_bcast:15
    x = dppadd<0x143>(x);   // row_bcast:31
    return x;
}

// GAT stage — r11 (DPP attention dots, 190 us) + smw ELIMINATION: the
// softmax denominator sum[d] = Σ_s exp(...) is the row-sum of P, which
// S5/S9 already materialize lane-wide (rdl broadcasts / p4 loads). Summing
// those values inline reproduces it exactly (duplicate edges accumulate
// identically into P; self-loops guarantee sum>0). This deletes the 4
// heavily-colliding DS atomics (64 lanes -> 14 addresses, ~5-way
// serialization each), the smS array, its zeroing and reads.
__global__ __launch_bounds__(256) void gat_k(
    const float* __restrict__ x, const int* __restrict__ ei,
    const float* __restrict__ W1, const float* __restrict__ as1,
    const float* __restrict__ ad1, const float* __restrict__ b1,
    const float* __restrict__ W2, const float* __restrict__ as2,
    const float* __restrict__ ad2, const float* __restrict__ b2,
    float* __restrict__ Gout) {
    __shared__ __align__(16) float HA[WPB][NN * HAP];   // A1 (S5->S6)
    __shared__ __align__(16) float H2S[WPB][NN * H2P];
    __shared__ __align__(16) float PS[WPB][PSZ];        // unnormalized exp rows
    __shared__ __align__(16) float sdS[WPB][2 * NN + 4]; // src/dst dots (f4-padded)
    __shared__ __align__(16) float a2S[2 * FD];
    __shared__ int esS[NE], edS[NE];

    const int tid = threadIdx.x;
    const int wv = tid >> 6;
    const int lane = tid & 63;
    float* HAw = HA[wv];
    float* H2w = H2S[wv];
    float* Pw = PS[wv];
    float* sdw = sdS[wv];

    if (tid < 2 * FD) a2S[tid] = (tid < FD) ? as2[tid] : ad2[tid - FD];
    // edge staging: robust to int64 (lo/hi dword pairs) or int32 delivery
    if (tid < 56) {
        int e64 = 1;
        for (int i = 0; i < 8; i++)
            if (ei[2 * i + 1] != 0 || (uu32)ei[2 * i] >= (uu32)NN) e64 = 0;
        esS[tid] = e64 ? ei[2 * tid] : ei[tid];
        edS[tid] = e64 ? ei[112 + 2 * tid] : ei[56 + tid];
    } else if (tid < NE) {
        esS[tid] = tid - 56;   // self loops
        edS[tid] = tid - 56;
    }

    // per-lane resident weights
    float w1r[FD];
#pragma unroll
    for (int f = 0; f < FD; f++) w1r[f] = W1[f * HD + lane];
    const float b1r = b1[lane];
    const float asr = as1[lane];   // conv1 attention vecs, lane = hidden k
    const float adr = ad1[lane];
    const int f2 = lane % FD;
    const int g2 = lane / FD;      // 0,1 active for 24-wide stages
    float w2r[HD];
#pragma unroll
    for (int k = 0; k < HD; k++) w2r[k] = W2[k * FD + f2];
    const float b2r = b2[f2];
    __syncthreads();   // the ONE block barrier: cross-wave staged a2S/es/ed
    // edge ownership: edge0 = lane (0..63); lanes 0..5 also own 64..69
    const bool ex = (lane < NE - 64);
    const int s0 = esS[lane], d0 = edS[lane];
    const int s1 = esS[ex ? 64 + lane : 0], d1 = edS[ex ? 64 + lane : 0];

    const int gw = blockIdx.x * WPB + wv;
#pragma unroll 1
    for (int t = 0; t < SPW; t++) {
        const size_t b = (size_t)gw * SPW + t;
        // ---- 1. X[b] per-lane into regs (coalesced); no LDS staging ----
        const float* __restrict__ xb = x + b * (NN * FD);
        float xr[6];
        xr[0] = xb[lane];
        xr[1] = xb[64 + lane];
        xr[2] = xb[128 + lane];
        xr[3] = xb[192 + lane];
        xr[4] = xb[256 + lane];
        xr[5] = (lane < NN * FD - 320) ? xb[320 + lane] : 0.0f;
        // ---- 2. H1 = X @ W1 (lane owns hidden col); X via readlane ----
        float acc[NN];
#pragma unroll
        for (int n = 0; n < NN; n++) acc[n] = 0.0f;
#pragma unroll
        for (int f = 0; f < FD; f++) {
#pragma unroll
            for (int n = 0; n < NN; n++) {
                const int i = f * NN + n;          // compile-time
                acc[n] = fmaf(rdl(xr[i >> 6], i & 63), w1r[f], acc[n]);
            }
        }
        // (H1 never touches LDS)
        // ---- 3. src/dst dots via DPP reduce over lanes (= hidden k) ----
        {
            float rs[NN];
#pragma unroll
            for (int n = 0; n < NN; n++) rs[n] = dppsum(acc[n] * asr);
            if (lane == 63) {
                *(float4*)&sdw[0] = make_float4(rs[0], rs[1], rs[2], rs[3]);
                *(float4*)&sdw[4] = make_float4(rs[4], rs[5], rs[6], rs[7]);
                *(float4*)&sdw[8] = make_float4(rs[8], rs[9], rs[10], rs[11]);
            }
            float rd[NN];
#pragma unroll
            for (int n = 0; n < NN; n++) rd[n] = dppsum(acc[n] * adr);
            if (lane == 63) {
                *(float4*)&sdw[12] = make_float4(rs[12], rs[13], rd[0], rd[1]);
                *(float4*)&sdw[16] = make_float4(rd[2], rd[3], rd[4], rd[5]);
                *(float4*)&sdw[20] = make_float4(rd[6], rd[7], rd[8], rd[9]);
                *(float4*)&sdw[24] = make_float4(rd[10], rd[11], rd[12], rd[13]);
            }
        }
        if (lane < PSZ / 4)
            *(float4*)&Pw[lane * 4] = make_float4(0.f, 0.f, 0.f, 0.f);
        WSYNC();
        // ---- 4. softmax1: edge exp -> P only (denominator = P row-sum) ----
        {
            float a = sdw[s0] + sdw[NN + d0];
            a = a > 0.0f ? a : 0.2f * a;               // leaky_relu(0.2)
            atomicAdd(&Pw[d0 * 16 + s0], __expf(a));   // unnormalized
            if (ex) {
                a = sdw[s1] + sdw[NN + d1];
                a = a > 0.0f ? a : 0.2f * a;
                atomicAdd(&Pw[d1 * 16 + s1], __expf(a));
            }
        }
        WSYNC();
        // ---- 5. A1 = ELU(P @ H1 / rowsum(P) + b1); P via rdl gather ----
        const float pr0 = Pw[lane];
        const float pr1 = Pw[64 + lane];
        const float pr2 = Pw[128 + lane];
        const float pr3 = (lane < PSZ - 192) ? Pw[192 + lane] : 0.0f;
        float acc2[NN];
#pragma unroll
        for (int n = 0; n < NN; n++) {
            float a = 0.0f, rs = 0.0f;
#pragma unroll
            for (int k = 0; k < NN; k++) {
                const int i = n * 16 + k;          // compile-time
                const float pv = (i < 64) ? rdl(pr0, i) :
                                 (i < 128) ? rdl(pr1, i - 64) :
                                 (i < 192) ? rdl(pr2, i - 128) :
                                             rdl(pr3, i - 192);
                a = fmaf(pv, acc[k], a);
                rs += pv;                          // softmax denominator
            }
            a = __fdividef(a, rs) + b1r;
            acc2[n] = a > 0.0f ? a : (__expf(a) - 1.0f);   // ELU
        }
#pragma unroll
        for (int n = 0; n < NN; n++) HAw[n * HAP + lane] = acc2[n];
        WSYNC();
        // ---- 6. H2 = A1 @ W2 : lane (g2,f2) covers 7 nodes ----
        if (g2 < 2) {
#pragma unroll
            for (int i = 0; i < 7; i++) {
                const int n = g2 + 2 * i;
                float a = 0.0f;
#pragma unroll
                for (int k4 = 0; k4 < 16; k4++) {
                    float4 v4 = *(const float4*)&HAw[n * HAP + 4 * k4];
                    a = fmaf(v4.x, w2r[4 * k4 + 0], a);
                    a = fmaf(v4.y, w2r[4 * k4 + 1], a);
                    a = fmaf(v4.z, w2r[4 * k4 + 2], a);
                    a = fmaf(v4.w, w2r[4 * k4 + 3], a);
                }
                H2w[n * H2P + f2] = a;
            }
        }
        WSYNC();
        // ---- 7. conv2 dots (28 lanes) + zero P ----
        if (lane < 2 * NN) {
            const int v = (lane >= NN) ? 1 : 0;
            const int n2 = lane - v * NN;
            float s = 0.0f;
#pragma unroll
            for (int q = 0; q < 6; q++) {
                float4 h4 = *(const float4*)&H2w[n2 * H2P + 4 * q];
                float4 a4 = *(const float4*)&a2S[v * FD + 4 * q];
                s = fmaf(h4.x, a4.x, s); s = fmaf(h4.y, a4.y, s);
                s = fmaf(h4.z, a4.z, s); s = fmaf(h4.w, a4.w, s);
            }
            sdw[v * NN + n2] = s;
        }
        if (lane < PSZ / 4)
            *(float4*)&Pw[lane * 4] = make_float4(0.f, 0.f, 0.f, 0.f);
        WSYNC();
        // ---- 8. softmax2: edge exp -> P only ----
        {
            float a = sdw[s0] + sdw[NN + d0];
            a = a > 0.0f ? a : 0.2f * a;
            atomicAdd(&Pw[d0 * 16 + s0], __expf(a));
            if (ex) {
                a = sdw[s1] + sdw[NN + d1];
                a = a > 0.0f ? a : 0.2f * a;
                atomicAdd(&Pw[d1 * 16 + s1], __expf(a));
            }
        }
        WSYNC();
        // ---- 9. G = P2 @ H2 / rowsum(P2) + b2 -> d_out [14][B][24] ----
        if (g2 < 2) {
            float h2c[NN];
#pragma unroll
            for (int k = 0; k < NN; k++) h2c[k] = H2w[k * H2P + f2];
#pragma unroll
            for (int i = 0; i < 7; i++) {
                const int n = g2 + 2 * i;
                float4 p0 = *(const float4*)&Pw[n * 16 + 0];
                float4 p1 = *(const float4*)&Pw[n * 16 + 4];
                float4 p2 = *(const float4*)&Pw[n * 16 + 8];
                float4 p3 = *(const float4*)&Pw[n * 16 + 12];
                float a = 0.0f;
                a = fmaf(p0.x, h2c[0], a);  a = fmaf(p0.y, h2c[1], a);
                a = fmaf(p0.z, h2c[2], a);  a = fmaf(p0.w, h2c[3], a);
                a = fmaf(p1.x, h2c[4], a);  a = fmaf(p1.y, h2c[5], a);
                a = fmaf(p1.z, h2c[6], a);  a = fmaf(p1.w, h2c[7], a);
                a = fmaf(p2.x, h2c[8], a);  a = fmaf(p2.y, h2c[9], a);
                a = fmaf(p2.z, h2c[10], a); a = fmaf(p2.w, h2c[11], a);
                a = fmaf(p3.x, h2c[12], a); a = fmaf(p3.y, h2c[13], a);
                const float rs = ((p0.x + p0.y) + (p0.z + p0.w))
                               + ((p1.x + p1.y) + (p1.z + p1.w))
                               + ((p2.x + p2.y) + (p2.z + p2.w))
                               + (p3.x + p3.y);
                Gout[((size_t)n * BB + b) * FD + f2] =
                    __fdividef(a, rs) + b2r;
            }
        }
        WSYNC();   // protect reused LDS before next sample (wave-local)
    }
}

// MLP stage, in place on d_out — EXACT round-0 baseline (best measured:
// 133-134 us, reproduced). Every deviation tried (2-row, scalar path,
// readlane streams, permlane split-reads, unroll-2 + hoist) measured
// 137-172 us — this shape is the empirical local optimum. DO NOT perturb.
__global__ __launch_bounds__(256) void mlp_k(
    const float* __restrict__ fc1w, const float* __restrict__ fc1b,
    const float* __restrict__ fc2w, const float* __restrict__ fc2b,
    float* gio) {
    __shared__ __align__(16) float W1L[FD * HD];
    __shared__ __align__(16) float W2L[HD * FD];
    __shared__ float B1L[HD];
    __shared__ float B2L[FD];

    const int t = threadIdx.x;
    const int n = blockIdx.x >> 7;             // 128 blocks per node
    const int b0 = (blockIdx.x & 127) * 256;

    const float4* w1p = (const float4*)(fc1w + (size_t)n * (FD * HD));
    const float4* w2p = (const float4*)(fc2w + (size_t)n * (HD * FD));
    for (int i = t; i < 384; i += 256) {
        *(float4*)&W1L[4 * i] = w1p[i];
        *(float4*)&W2L[4 * i] = w2p[i];
    }
    if (t < HD) B1L[t] = fc1b[n * HD + t];
    if (t < FD) B2L[t] = fc2b[n * FD + t];
    __syncthreads();

    const size_t base = ((size_t)n * BB + b0 + t) * FD;
    float g[FD], o[FD];
#pragma unroll
    for (int q = 0; q < 6; q++)
        *(float4*)&g[4 * q] = *(const float4*)&gio[base + 4 * q];
#pragma unroll
    for (int f = 0; f < FD; f++) o[f] = B2L[f];

#pragma unroll
    for (int j4 = 0; j4 < 16; j4++) {
        float h0 = B1L[4 * j4 + 0], h1 = B1L[4 * j4 + 1];
        float h2 = B1L[4 * j4 + 2], h3 = B1L[4 * j4 + 3];
#pragma unroll
        for (int f = 0; f < FD; f++) {
            float4 w4 = *(const float4*)&W1L[f * HD + 4 * j4];   // broadcast
            h0 = fmaf(g[f], w4.x, h0);
            h1 = fmaf(g[f], w4.y, h1);
            h2 = fmaf(g[f], w4.z, h2);
            h3 = fmaf(g[f], w4.w, h3);
        }
        h0 = fmaxf(h0, 0.f); h1 = fmaxf(h1, 0.f);
        h2 = fmaxf(h2, 0.f); h3 = fmaxf(h3, 0.f);
        float hv[4] = {h0, h1, h2, h3};
#pragma unroll
        for (int u2 = 0; u2 < 4; u2++) {
            const int j = 4 * j4 + u2;
#pragma unroll
            for (int f4 = 0; f4 < 6; f4++) {
                float4 w4 = *(const float4*)&W2L[j * FD + 4 * f4];   // broadcast
                o[4 * f4 + 0] = fmaf(hv[u2], w4.x, o[4 * f4 + 0]);
                o[4 * f4 + 1] = fmaf(hv[u2], w4.y, o[4 * f4 + 1]);
                o[4 * f4 + 2] = fmaf(hv[u2], w4.z, o[4 * f4 + 2]);
                o[4 * f4 + 3] = fmaf(hv[u2], w4.w, o[4 * f4 + 3]);
            }
        }
    }
#pragma unroll
    for (int q = 0; q < 6; q++)
        *(float4*)&gio[base + 4 * q] = *(const float4*)&o[4 * q];
}

extern "C" void kernel_launch(void* const* d_in, const int* in_sizes, int n_in,
                              void* d_out, int out_size, void* d_ws, size_t ws_size,
                              hipStream_t stream) {
    (void)in_sizes; (void)n_in; (void)out_size; (void)d_ws; (void)ws_size;
    const float* x    = (const float*)d_in[0];
    const int*   ei   = (const int*)d_in[1];
    const float* W1   = (const float*)d_in[2];
    const float* as1  = (const float*)d_in[3];
    const float* ad1  = (const float*)d_in[4];
    const float* b1   = (const float*)d_in[5];
    const float* W2   = (const float*)d_in[6];
    const float* as2  = (const float*)d_in[7];
    const float* ad2  = (const float*)d_in[8];
    const float* b2   = (const float*)d_in[9];
    const float* fc1w = (const float*)d_in[10];
    const float* fc1b = (const float*)d_in[11];
    const float* fc2w = (const float*)d_in[12];
    const float* fc2b = (const float*)d_in[13];
    float* gio = (float*)d_out;   // G staged in d_out, MLP rewrites in place

    gat_k<<<dim3(K1_BLOCKS), dim3(256), 0, stream>>>(
        x, ei, W1, as1, ad1, b1, W2, as2, ad2, b2, gio);
    mlp_k<<<dim3(K2_BLOCKS), dim3(256), 0, stream>>>(
        fc1w, fc1b, fc2w, fc2b, gio);
}